// Round 10
// baseline (81.568 us; speedup 1.0000x reference)
//
#include <hip/hip_runtime.h>
#include <stdint.h>

// Problem constants (fixed by the reference): B=2, S=2048, D=1024, H=16, dh=64, WINDOW=256
static constexpr int Ss = 2048;
static constexpr int Dd = 1024;
static constexpr int Hh = 16;
static constexpr int DH = 64;

typedef short bf16x8 __attribute__((ext_vector_type(8)));
typedef float f32x4 __attribute__((ext_vector_type(4)));
typedef uint32_t u32x4 __attribute__((ext_vector_type(4)));

#define LOG2E 1.4426950408889634f

__device__ __forceinline__ uint16_t f2bf(float f) {
  uint32_t u = __builtin_bit_cast(uint32_t, f);
  u += 0x7fffu + ((u >> 16) & 1u);   // RNE (finite data only)
  return (uint16_t)(u >> 16);
}
__device__ __forceinline__ float bf2f(uint16_t h) {
  uint32_t u = ((uint32_t)h) << 16;
  return __builtin_bit_cast(float, u);
}
__device__ __forceinline__ uint32_t cvtpk(float a, float b) {
  uint32_t r;
  asm("v_cvt_pk_bf16_f32 %0, %1, %2" : "=v"(r) : "v"(a), "v"(b));
  return r;
}

// DPP lane-rotate within 16-lane rows (pure VALU, no LDS pipe).
template <int CTRL>
__device__ __forceinline__ float dppf(float x) {
  return __builtin_bit_cast(float,
      __builtin_amdgcn_update_dpp(0, __builtin_bit_cast(int, x), CTRL, 0xF, 0xF, true));
}
__device__ __forceinline__ float rowsum16(float v) {
  v += dppf<0x128>(v);
  v += dppf<0x124>(v);
  v += dppf<0x122>(v);
  v += dppf<0x121>(v);
  return v;
}
__device__ __forceinline__ float fexp2(float x) { return __builtin_amdgcn_exp2f(x); }

#define GAS(p) ((const __attribute__((address_space(1))) uint32_t*)(p))
#define LAS(p) ((__attribute__((address_space(3))) uint32_t*)(p))

// ---------------- f32 -> bf16 conversion: 4 weights only (1024 blocks each) ----------------
__global__ void cvt_w(const float* __restrict__ w0, const float* __restrict__ w1,
                      const float* __restrict__ w2, const float* __restrict__ w3,
                      uint16_t* __restrict__ o0, uint16_t* __restrict__ o1,
                      uint16_t* __restrict__ o2, uint16_t* __restrict__ o3) {
  int bid = blockIdx.x;
  int t = bid >> 10;
  const float* in = (t == 0) ? w0 : (t == 1) ? w1 : (t == 2) ? w2 : w3;
  uint16_t* out = (t == 0) ? o0 : (t == 1) ? o1 : (t == 2) ? o2 : o3;
  int i = (bid & 1023) * 256 + threadIdx.x;   // 262144 float4 exactly per tensor
  float4 v = reinterpret_cast<const float4*>(in)[i];
  ushort4 o;
  o.x = f2bf(v.x); o.y = f2bf(v.y); o.z = f2bf(v.z); o.w = f2bf(v.w);
  reinterpret_cast<ushort4*>(out)[i] = o;
}

// ---------------- QKV GEMM: C = X[f32] * W^T + bias, pipelined A-path ----------------
// BM=128, BN=128, BK=64, 256 threads (4 waves, 2x2), per-wave 64x64 output.
// A is reg-staged from f32 x with inline bf16 conversion into a DOUBLE-BUFFERED
// A-LDS; next tile's A-loads stay in flight across the barrier (vmcnt(8) counted
// wait drains only the 4 B global_load_lds). Output: bf16 QKV [B,H,S,dh].
__global__ __launch_bounds__(256, 2) void gemm_qkv(
    const float* __restrict__ X,
    const uint16_t* __restrict__ W0, const uint16_t* __restrict__ W1, const uint16_t* __restrict__ W2,
    const float* __restrict__ b0, const float* __restrict__ b1, const float* __restrict__ b2,
    uint16_t* __restrict__ O0, uint16_t* __restrict__ O1, uint16_t* __restrict__ O2) {
  constexpr int K = 1024;
  __shared__ __align__(16) uint8_t ldsA[2][128 * 128];  // dbuf [128 m][64 k] bf16, swizzled
  __shared__ __align__(16) uint8_t ldsB[128 * 128];     // [128 n][64 k] bf16, swizzled

  const int tid = threadIdx.x, w = tid >> 6, lane = tid & 63;
  const int q = lane & 15, g = lane >> 4;
  const int wm = w >> 1, wn = w & 1;
  const int bx = blockIdx.x, by = blockIdx.y, z = blockIdx.z;
  const uint16_t* Wp = (z == 0) ? W0 : (z == 1) ? W1 : W2;
  const float* bp = (z == 0) ? b0 : (z == 1) ? b1 : b2;
  uint16_t* Op = (z == 0) ? O0 : (z == 1) ? O1 : O2;

  // per-lane A staging geometry (same linear-LDS / inverse-swizzled-source map)
  int arow[4], aelem[4];
#pragma unroll
  for (int i = 0; i < 4; ++i) {
    int Lb = w * 4096 + i * 1024 + lane * 16;
    int row = Lb >> 7, cb = Lb & 127;
    arow[i] = row;
    aelem[i] = (cb ^ ((row & 7) << 4)) >> 1;
  }

  f32x4 acc[4][4] = {};
  float4 ar[4][2];

  // prologue: issue A(0) loads (f32, 2x dwordx4 per slot)
#pragma unroll
  for (int i = 0; i < 4; ++i) {
    const float* s = X + (size_t)(bx * 128 + arow[i]) * K + aelem[i];
    ar[i][0] = *(const float4*)s;
    ar[i][1] = *(const float4*)(s + 4);
  }

  const int nkt = K >> 6;
  for (int kt = 0; kt < nkt; ++kt) {
    const int k0 = kt << 6;
    const int cur = kt & 1;

    __builtin_amdgcn_s_barrier();           // all waves done reading previous tile
    __builtin_amdgcn_sched_barrier(0);
    // stage B(kt): 4 gll/wave
#pragma unroll
    for (int i = 0; i < 4; ++i) {
      int Lb = w * 4096 + i * 1024 + lane * 16;
      int row = Lb >> 7, cb = Lb & 127;
      const uint16_t* srcB = Wp + (size_t)(by * 128 + row) * K + k0 + ((cb ^ ((row & 7) << 4)) >> 1);
      __builtin_amdgcn_global_load_lds(GAS(srcB), LAS(ldsB + w * 4096 + i * 1024), 16, 0, 0);
    }
    __builtin_amdgcn_sched_barrier(0);
    // cvt A regs -> bf16 -> ds_write dbuf[cur]  (compiler waits vmcnt for ar deps)
#pragma unroll
    for (int i = 0; i < 4; ++i) {
      u32x4 pk;
      pk[0] = cvtpk(ar[i][0].x, ar[i][0].y);
      pk[1] = cvtpk(ar[i][0].z, ar[i][0].w);
      pk[2] = cvtpk(ar[i][1].x, ar[i][1].y);
      pk[3] = cvtpk(ar[i][1].z, ar[i][1].w);
      *(u32x4*)(ldsA[cur] + w * 4096 + i * 1024 + lane * 16) = pk;
    }
    __builtin_amdgcn_sched_barrier(0);
    if (kt + 1 < nkt) {
      // issue A(kt+1) loads; they stay in flight across the barrier
#pragma unroll
      for (int i = 0; i < 4; ++i) {
        const float* s = X + (size_t)(bx * 128 + arow[i]) * K + (k0 + 64) + aelem[i];
        ar[i][0] = *(const float4*)s;
        ar[i][1] = *(const float4*)(s + 4);
      }
      __builtin_amdgcn_sched_barrier(0);
      asm volatile("s_waitcnt vmcnt(8) lgkmcnt(0)" ::: "memory");  // drain 4 B glls only
    } else {
      asm volatile("s_waitcnt vmcnt(0) lgkmcnt(0)" ::: "memory");
    }
    __builtin_amdgcn_sched_barrier(0);
    __builtin_amdgcn_s_barrier();
    __builtin_amdgcn_sched_barrier(0);

    // fragments + MFMA
    bf16x8 af[4][2], bfg[4][2];
#pragma unroll
    for (int mi = 0; mi < 4; ++mi)
#pragma unroll
      for (int s = 0; s < 2; ++s) {
        int row = wm * 64 + mi * 16 + q;
        int cb = (16 * g + 64 * s) ^ ((row & 7) << 4);
        af[mi][s] = *(const bf16x8*)(ldsA[cur] + row * 128 + cb);
      }
#pragma unroll
    for (int ni = 0; ni < 4; ++ni)
#pragma unroll
      for (int s = 0; s < 2; ++s) {
        int row = wn * 64 + ni * 16 + q;
        int cb = (16 * g + 64 * s) ^ ((row & 7) << 4);
        bfg[ni][s] = *(const bf16x8*)(ldsB + row * 128 + cb);
      }
#pragma unroll
    for (int mi = 0; mi < 4; ++mi)
#pragma unroll
      for (int ni = 0; ni < 4; ++ni) {
        acc[mi][ni] = __builtin_amdgcn_mfma_f32_16x16x32_bf16(af[mi][0], bfg[ni][0], acc[mi][ni], 0, 0, 0);
        acc[mi][ni] = __builtin_amdgcn_mfma_f32_16x16x32_bf16(af[mi][1], bfg[ni][1], acc[mi][ni], 0, 0, 0);
      }
  }

  // epilogue: bias + store to [B,H,S,dh].  C/D: col=lane&15, row=(lane>>4)*4+reg
  float bias[4];
#pragma unroll
  for (int ni = 0; ni < 4; ++ni) bias[ni] = bp[by * 128 + wn * 64 + ni * 16 + q];
#pragma unroll
  for (int mi = 0; mi < 4; ++mi)
#pragma unroll
    for (int ni = 0; ni < 4; ++ni)
#pragma unroll
      for (int r = 0; r < 4; ++r) {
        int m = bx * 128 + wm * 64 + mi * 16 + 4 * g + r;
        int n = by * 128 + wn * 64 + ni * 16 + q;
        float v = acc[mi][ni][r] + bias[ni];
        int b = m >> 11, s = m & 2047, h = n >> 6, d = n & 63;
        Op[(((size_t)(b * Hh + h) * Ss + s) << 6) + d] = f2bf(v);
      }
}

// ---------------- out-projection GEMM (bf16 A via gll, unchanged structure) ----------------
// BM=128, BN=64, BK=64, 256 threads (4 waves, 2x2). f32 output row-major.
__global__ __launch_bounds__(256, 2) void gemm_out(
    const uint16_t* __restrict__ A, const uint16_t* __restrict__ W,
    const float* __restrict__ bp, float* __restrict__ O, int M, int N, int K) {
  __shared__ __align__(16) uint8_t ldsA[128 * 128];
  __shared__ __align__(16) uint8_t ldsB[64 * 128];

  const int tid = threadIdx.x, w = tid >> 6, lane = tid & 63;
  const int q = lane & 15, g = lane >> 4;
  const int wm = w >> 1, wn = w & 1;
  const int bx = blockIdx.x, by = blockIdx.y;

  f32x4 acc[4][2] = {};

  const int nkt = K >> 6;
  for (int kt = 0; kt < nkt; ++kt) {
    const int k0 = kt << 6;
    __syncthreads();
#pragma unroll
    for (int i = 0; i < 4; ++i) {
      int Lb = w * 4096 + i * 1024 + lane * 16;
      int row = Lb >> 7, cb = Lb & 127;
      const uint16_t* srcA = A + (size_t)(bx * 128 + row) * K + k0 + ((cb ^ ((row & 7) << 4)) >> 1);
      __builtin_amdgcn_global_load_lds(GAS(srcA), LAS(ldsA + w * 4096 + i * 1024), 16, 0, 0);
    }
#pragma unroll
    for (int i = 0; i < 2; ++i) {
      int Lb = w * 2048 + i * 1024 + lane * 16;
      int row = Lb >> 7, cb = Lb & 127;
      const uint16_t* srcB = W + (size_t)(by * 64 + row) * K + k0 + ((cb ^ ((row & 7) << 4)) >> 1);
      __builtin_amdgcn_global_load_lds(GAS(srcB), LAS(ldsB + w * 2048 + i * 1024), 16, 0, 0);
    }
    __syncthreads();

    bf16x8 af[4][2], bfg[2][2];
#pragma unroll
    for (int mi = 0; mi < 4; ++mi)
#pragma unroll
      for (int s = 0; s < 2; ++s) {
        int row = wm * 64 + mi * 16 + q;
        int cb = (16 * g + 64 * s) ^ ((row & 7) << 4);
        af[mi][s] = *(const bf16x8*)(ldsA + row * 128 + cb);
      }
#pragma unroll
    for (int ni = 0; ni < 2; ++ni)
#pragma unroll
      for (int s = 0; s < 2; ++s) {
        int row = wn * 32 + ni * 16 + q;
        int cb = (16 * g + 64 * s) ^ ((row & 7) << 4);
        bfg[ni][s] = *(const bf16x8*)(ldsB + row * 128 + cb);
      }
#pragma unroll
    for (int mi = 0; mi < 4; ++mi)
#pragma unroll
      for (int ni = 0; ni < 2; ++ni) {
        acc[mi][ni] = __builtin_amdgcn_mfma_f32_16x16x32_bf16(af[mi][0], bfg[ni][0], acc[mi][ni], 0, 0, 0);
        acc[mi][ni] = __builtin_amdgcn_mfma_f32_16x16x32_bf16(af[mi][1], bfg[ni][1], acc[mi][ni], 0, 0, 0);
      }
  }

  float bias[2];
#pragma unroll
  for (int ni = 0; ni < 2; ++ni) bias[ni] = bp[by * 64 + wn * 32 + ni * 16 + q];
#pragma unroll
  for (int mi = 0; mi < 4; ++mi)
#pragma unroll
    for (int ni = 0; ni < 2; ++ni)
#pragma unroll
      for (int r = 0; r < 4; ++r) {
        int m = bx * 128 + wm * 64 + mi * 16 + 4 * g + r;
        int n = by * 64 + wn * 32 + ni * 16 + q;
        O[(size_t)m * N + n] = acc[mi][ni][r] + bias[ni];
      }
}

// ---------------- sliding-window attention (round-9 structure, unchanged) ----------------
__global__ __launch_bounds__(512, 4) void attn_swa(
    const uint16_t* __restrict__ Qg, const uint16_t* __restrict__ Kg,
    const uint16_t* __restrict__ Vg, uint16_t* __restrict__ Og) {
  __shared__ __align__(16) uint8_t ldsK[2][64 * 128];
  __shared__ __align__(16) uint8_t ldsVt[2][64 * 128];
  __shared__ __align__(16) uint8_t ldsP[8][2048];

  const int tid = threadIdx.x, w = tid >> 6, lane = tid & 63;
  const int q = lane & 15, g = lane >> 4;
  const int qb = blockIdx.x, bh = blockIdx.y;
  const size_t hbase = (size_t)bh * Ss * DH;
  const uint16_t* Qp = Qg + hbase;
  const uint16_t* Kp = Kg + hbase;
  const uint16_t* Vp = Vg + hbase;
  const int q0 = qb * 128;
  const int qw = q0 + w * 16;

  bf16x8 aq[2];
#pragma unroll
  for (int s = 0; s < 2; ++s) {
    bf16x8 t = *(const bf16x8*)(Qp + (size_t)(qw + q) * DH + s * 32 + g * 8);
#pragma unroll
    for (int j = 0; j < 8; ++j) {
      float f = bf2f((uint16_t)t[j]) * 0.125f;
      t[j] = (short)f2bf(f);
    }
    aq[s] = t;
  }

  f32x4 accO[4] = {};
  float lrun[4] = {0.f, 0.f, 0.f, 0.f};

  const int t0 = (q0 >= 256) ? (q0 - 256) : 0;
  const int t1 = (q0 + 384 <= Ss) ? (q0 + 384) : Ss;
  const int nt = (t1 - t0) >> 6;

  {
    int Lb = w * 1024 + lane * 16;
    int row = Lb >> 7, cb = Lb & 127;
    const uint16_t* srcK = Kp + (size_t)(t0 + row) * DH + ((cb ^ ((row & 7) << 4)) >> 1);
    __builtin_amdgcn_global_load_lds(GAS(srcK), LAS(ldsK[0] + w * 1024), 16, 0, 0);
  }
  bf16x8 v0 = *(const bf16x8*)(Vp + (size_t)(t0 + lane) * DH + w * 8);

  for (int t = 0; t < nt; ++t) {
    const int kb0 = t0 + (t << 6);
    const int cur = t & 1, nxt = cur ^ 1;

    asm volatile("s_waitcnt vmcnt(0)" ::: "memory");
    uint8_t* Vt = ldsVt[cur];
#pragma unroll
    for (int j = 0; j < 8; ++j) {
      int c = w * 8 + j;
      *(uint16_t*)(Vt + c * 128 + ((2 * lane) ^ (j << 4))) = (uint16_t)v0[j];
    }
    asm volatile("s_waitcnt lgkmcnt(0)" ::: "memory");
    __builtin_amdgcn_sched_barrier(0);
    __builtin_amdgcn_s_barrier();
    __builtin_amdgcn_sched_barrier(0);

    if (t + 1 < nt) {
      int Lb = w * 1024 + lane * 16;
      int row = Lb >> 7, cb = Lb & 127;
      const uint16_t* srcK = Kp + (size_t)(kb0 + 64 + row) * DH + ((cb ^ ((row & 7) << 4)) >> 1);
      __builtin_amdgcn_global_load_lds(GAS(srcK), LAS(ldsK[nxt] + w * 1024), 16, 0, 0);
      v0 = *(const bf16x8*)(Vp + (size_t)(kb0 + 64 + lane) * DH + w * 8);
    }

    const int dtile = kb0 - qw;
    if (dtile >= -319 && dtile <= 271) {
      const uint8_t* Kl = ldsK[cur];
      f32x4 sacc[4] = {};
#pragma unroll
      for (int kb = 0; kb < 4; ++kb) {
        int row = kb * 16 + q;
#pragma unroll
        for (int s = 0; s < 2; ++s) {
          int cb = (16 * g + 64 * s) ^ ((row & 7) << 4);
          bf16x8 bk = *(const bf16x8*)(Kl + row * 128 + cb);
          sacc[kb] = __builtin_amdgcn_mfma_f32_16x16x32_bf16(aq[s], bk, sacc[kb], 0, 0, 0);
        }
      }
      if (dtile < -192 || dtile > 192) {
#pragma unroll
        for (int kb = 0; kb < 4; ++kb) {
          int key = kb0 + kb * 16 + q;
#pragma unroll
          for (int r = 0; r < 4; ++r) {
            int qi = qw + 4 * g + r;
            int dd = qi - key;
            bool ok = (dd <= 256) && (dd >= -256);
            sacc[kb][r] = ok ? sacc[kb][r] : -1e30f;
          }
        }
      }
      uint8_t* Pl = ldsP[w];
#pragma unroll
      for (int r = 0; r < 4; ++r) {
        float p0 = fexp2(sacc[0][r] * LOG2E);
        float p1 = fexp2(sacc[1][r] * LOG2E);
        float p2 = fexp2(sacc[2][r] * LOG2E);
        float p3 = fexp2(sacc[3][r] * LOG2E);
        float rs = rowsum16((p0 + p1) + (p2 + p3));
        lrun[r] += rs;
        int prow = 4 * g + r;
        int sw = (prow & 7) << 4;
        uint8_t* Pr = Pl + prow * 128;
        uint32_t pk01 = cvtpk(p0, p1), pk23 = cvtpk(p2, p3);
        *(uint16_t*)(Pr + ((2 * q) ^ sw))      = (uint16_t)pk01;
        *(uint16_t*)(Pr + ((2 * q + 32) ^ sw)) = (uint16_t)(pk01 >> 16);
        *(uint16_t*)(Pr + ((2 * q + 64) ^ sw)) = (uint16_t)pk23;
        *(uint16_t*)(Pr + ((2 * q + 96) ^ sw)) = (uint16_t)(pk23 >> 16);
      }
      bf16x8 ap[2];
#pragma unroll
      for (int s = 0; s < 2; ++s) {
        int cb = (16 * g + 64 * s) ^ ((q & 7) << 4);
        ap[s] = *(const bf16x8*)(Pl + q * 128 + cb);
      }
#pragma unroll
      for (int db = 0; db < 4; ++db) {
        int vr = db * 16 + q;
#pragma unroll
        for (int s = 0; s < 2; ++s) {
          int cb = (64 * s + 16 * g) ^ ((vr & 7) << 4);
          bf16x8 bvf = *(const bf16x8*)(ldsVt[cur] + vr * 128 + cb);
          accO[db] = __builtin_amdgcn_mfma_f32_16x16x32_bf16(ap[s], bvf, accO[db], 0, 0, 0);
        }
      }
    }
  }

  const int b2 = bh >> 4, h = bh & 15;
#pragma unroll
  for (int r = 0; r < 4; ++r) {
    float inv = 1.0f / lrun[r];
    int qi = qw + 4 * g + r;
    size_t rowbase = ((size_t)(b2 * Ss + qi)) * Dd + h * DH;
#pragma unroll
    for (int db = 0; db < 4; ++db) {
      Og[rowbase + db * 16 + q] = f2bf(accO[db][r] * inv);
    }
  }
}

// ---------------- host launch ----------------
extern "C" void kernel_launch(void* const* d_in, const int* in_sizes, int n_in,
                              void* d_out, int out_size, void* d_ws, size_t ws_size,
                              hipStream_t stream) {
  const float* x  = (const float*)d_in[0];
  const float* wq = (const float*)d_in[1];
  const float* bq = (const float*)d_in[2];
  const float* wk = (const float*)d_in[3];
  const float* bk = (const float*)d_in[4];
  const float* wv = (const float*)d_in[5];
  const float* bv = (const float*)d_in[6];
  const float* wo = (const float*)d_in[7];
  const float* bo = (const float*)d_in[8];
  float* out = (float*)d_out;

  uint8_t* ws = (uint8_t*)d_ws;
  uint16_t* wqb = (uint16_t*)(ws + (size_t)(0u  << 20));  // 2 MB each
  uint16_t* wkb = (uint16_t*)(ws + (size_t)(2u  << 20));
  uint16_t* wvb = (uint16_t*)(ws + (size_t)(4u  << 20));
  uint16_t* wob = (uint16_t*)(ws + (size_t)(6u  << 20));
  uint16_t* Qb  = (uint16_t*)(ws + (size_t)(8u  << 20));  // 8 MB each
  uint16_t* Kb  = (uint16_t*)(ws + (size_t)(16u << 20));
  uint16_t* Vb  = (uint16_t*)(ws + (size_t)(24u << 20));
  uint16_t* AOb = (uint16_t*)(ws + (size_t)(32u << 20));  // attention output bf16 [4096,1024]

  // weights f32 -> bf16 (x is consumed in f32 directly by gemm_qkv)
  cvt_w<<<4096, 256, 0, stream>>>(wq, wk, wv, wo, wqb, wkb, wvb, wob);

  // fused QKV projection with pipelined f32-A staging
  gemm_qkv<<<dim3(32, 8, 3), 256, 0, stream>>>(
      x, wqb, wkb, wvb, bq, bk, bv, Qb, Kb, Vb);

  // sliding-window attention: QBLK=128, 8 waves x 16 q-rows
  attn_swa<<<dim3(16, 32), 512, 0, stream>>>(Qb, Kb, Vb, AOb);

  // output projection -> f32 d_out; BN=64 -> 512 WGs
  gemm_out<<<dim3(32, 16), 256, 0, stream>>>(
      AOb, wob, bo, out, 4096, 1024, 1024);
}

// Round 11
// 78.941 us; speedup vs baseline: 1.0333x; 1.0333x over previous
//
#include <hip/hip_runtime.h>
#include <stdint.h>

// Problem constants: B=2, S=2048, D=1024, H=16, dh=64, WINDOW=256
static constexpr int Ss = 2048;
static constexpr int Dd = 1024;
static constexpr int Hh = 16;
static constexpr int DH = 64;

typedef short bf16x8 __attribute__((ext_vector_type(8)));
typedef float f32x4 __attribute__((ext_vector_type(4)));

#define LOG2E 1.4426950408889634f

__device__ __forceinline__ uint16_t f2bf(float f) {
  uint32_t u = __builtin_bit_cast(uint32_t, f);
  u += 0x7fffu + ((u >> 16) & 1u);   // RNE (finite data only)
  return (uint16_t)(u >> 16);
}
__device__ __forceinline__ float bf2f(uint16_t h) {
  uint32_t u = ((uint32_t)h) << 16;
  return __builtin_bit_cast(float, u);
}
__device__ __forceinline__ uint32_t cvtpk(float a, float b) {
  uint32_t r;
  asm("v_cvt_pk_bf16_f32 %0, %1, %2" : "=v"(r) : "v"(a), "v"(b));
  return r;
}

// DPP lane-rotate within 16-lane rows (pure VALU, no LDS pipe).
template <int CTRL>
__device__ __forceinline__ float dppf(float x) {
  return __builtin_bit_cast(float,
      __builtin_amdgcn_update_dpp(0, __builtin_bit_cast(int, x), CTRL, 0xF, 0xF, true));
}
__device__ __forceinline__ float rowsum16(float v) {
  v += dppf<0x128>(v);
  v += dppf<0x124>(v);
  v += dppf<0x122>(v);
  v += dppf<0x121>(v);
  return v;
}
__device__ __forceinline__ float fexp2(float x) { return __builtin_amdgcn_exp2f(x); }

#define GAS(p) ((const __attribute__((address_space(1))) uint32_t*)(p))
#define LAS(p) ((__attribute__((address_space(3))) uint32_t*)(p))

// ---------------- f32 -> bf16: x (4096 blocks) + 4 weights (1024 blocks each) ----------------
__global__ void cvt_all(const float* __restrict__ x,
                        const float* __restrict__ w0, const float* __restrict__ w1,
                        const float* __restrict__ w2, const float* __restrict__ w3,
                        uint16_t* __restrict__ xb,
                        uint16_t* __restrict__ o0, uint16_t* __restrict__ o1,
                        uint16_t* __restrict__ o2, uint16_t* __restrict__ o3) {
  int bid = blockIdx.x;
  const float* in;
  uint16_t* out;
  int i;
  if (bid < 4096) {                       // x: 1048576 float4 exactly
    in = x; out = xb; i = bid * 256 + threadIdx.x;
  } else {                                // weights: 262144 float4 each exactly
    int b2 = bid - 4096;
    int t = b2 >> 10;
    in = (t == 0) ? w0 : (t == 1) ? w1 : (t == 2) ? w2 : w3;
    out = (t == 0) ? o0 : (t == 1) ? o1 : (t == 2) ? o2 : o3;
    i = (b2 & 1023) * 256 + threadIdx.x;
  }
  float4 v = reinterpret_cast<const float4*>(in)[i];
  ushort4 o;
  o.x = f2bf(v.x); o.y = f2bf(v.y); o.z = f2bf(v.z); o.w = f2bf(v.w);
  reinterpret_cast<ushort4*>(out)[i] = o;
}

// ---------------- QKV GEMM (round-9 proven structure): C = A * W^T + bias ----------------
// BM=128, BN=128, BK=64, 256 threads (4 waves, 2x2). bf16 out to [B,H,S,dh], z picks q/k/v.
__global__ __launch_bounds__(256, 2) void gemm_qkv(
    const uint16_t* __restrict__ A,
    const uint16_t* __restrict__ W0, const uint16_t* __restrict__ W1, const uint16_t* __restrict__ W2,
    const float* __restrict__ b0, const float* __restrict__ b1, const float* __restrict__ b2,
    uint16_t* __restrict__ O0, uint16_t* __restrict__ O1, uint16_t* __restrict__ O2) {
  constexpr int K = 1024;
  __shared__ __align__(16) uint8_t ldsA[128 * 128];  // [128 m][64 k] bf16, XOR-swizzled rows
  __shared__ __align__(16) uint8_t ldsB[128 * 128];  // [128 n][64 k] bf16, XOR-swizzled rows

  const int tid = threadIdx.x, w = tid >> 6, lane = tid & 63;
  const int q = lane & 15, g = lane >> 4;
  const int wm = w >> 1, wn = w & 1;
  const int bx = blockIdx.x, by = blockIdx.y, z = blockIdx.z;
  const uint16_t* Wp = (z == 0) ? W0 : (z == 1) ? W1 : W2;
  const float* bp = (z == 0) ? b0 : (z == 1) ? b1 : b2;
  uint16_t* Op = (z == 0) ? O0 : (z == 1) ? O1 : O2;

  f32x4 acc[4][4] = {};

  const int nkt = K >> 6;
  for (int kt = 0; kt < nkt; ++kt) {
    const int k0 = kt << 6;
    __syncthreads();  // all reads of previous tile done
#pragma unroll
    for (int i = 0; i < 4; ++i) {
      int Lb = w * 4096 + i * 1024 + lane * 16;
      int row = Lb >> 7, cb = Lb & 127;
      int col = (cb ^ ((row & 7) << 4)) >> 1;
      const uint16_t* srcA = A + (size_t)(bx * 128 + row) * K + k0 + col;
      __builtin_amdgcn_global_load_lds(GAS(srcA), LAS(ldsA + w * 4096 + i * 1024), 16, 0, 0);
      const uint16_t* srcB = Wp + (size_t)(by * 128 + row) * K + k0 + col;
      __builtin_amdgcn_global_load_lds(GAS(srcB), LAS(ldsB + w * 4096 + i * 1024), 16, 0, 0);
    }
    __syncthreads();  // vmcnt(0) drain emitted by compiler before barrier

    bf16x8 af[4][2], bfg[4][2];
#pragma unroll
    for (int mi = 0; mi < 4; ++mi)
#pragma unroll
      for (int s = 0; s < 2; ++s) {
        int row = wm * 64 + mi * 16 + q;
        int cb = (16 * g + 64 * s) ^ ((row & 7) << 4);
        af[mi][s] = *(const bf16x8*)(ldsA + row * 128 + cb);
      }
#pragma unroll
    for (int ni = 0; ni < 4; ++ni)
#pragma unroll
      for (int s = 0; s < 2; ++s) {
        int row = wn * 64 + ni * 16 + q;
        int cb = (16 * g + 64 * s) ^ ((row & 7) << 4);
        bfg[ni][s] = *(const bf16x8*)(ldsB + row * 128 + cb);
      }
#pragma unroll
    for (int mi = 0; mi < 4; ++mi)
#pragma unroll
      for (int ni = 0; ni < 4; ++ni) {
        acc[mi][ni] = __builtin_amdgcn_mfma_f32_16x16x32_bf16(af[mi][0], bfg[ni][0], acc[mi][ni], 0, 0, 0);
        acc[mi][ni] = __builtin_amdgcn_mfma_f32_16x16x32_bf16(af[mi][1], bfg[ni][1], acc[mi][ni], 0, 0, 0);
      }
  }

  float bias[4];
#pragma unroll
  for (int ni = 0; ni < 4; ++ni) bias[ni] = bp[by * 128 + wn * 64 + ni * 16 + q];
#pragma unroll
  for (int mi = 0; mi < 4; ++mi)
#pragma unroll
    for (int ni = 0; ni < 4; ++ni)
#pragma unroll
      for (int r = 0; r < 4; ++r) {
        int m = bx * 128 + wm * 64 + mi * 16 + 4 * g + r;
        int n = by * 128 + wn * 64 + ni * 16 + q;
        float v = acc[mi][ni][r] + bias[ni];
        int b = m >> 11, s = m & 2047, h = n >> 6, d = n & 63;
        Op[(((size_t)(b * Hh + h) * Ss + s) << 6) + d] = f2bf(v);
      }
}

// ---------------- out-projection GEMM: single-barrier double-buffered prefetch ----------------
// BM=128, BN=64, BK=64, 256 threads (4 waves, 2x2). f32 output row-major.
// Per iter: vmcnt(0) (drain glls for cur, issued one iter ago -> latency hid under
// prev MFMA), barrier, issue glls(t+1 -> nxt), compute cur. LDS 48KB -> 2 blocks/CU.
__global__ __launch_bounds__(256, 2) void gemm_out(
    const uint16_t* __restrict__ A, const uint16_t* __restrict__ W,
    const float* __restrict__ bp, float* __restrict__ O, int M, int N, int K) {
  __shared__ __align__(16) uint8_t ldsA[2][128 * 128];
  __shared__ __align__(16) uint8_t ldsB[2][64 * 128];

  const int tid = threadIdx.x, w = tid >> 6, lane = tid & 63;
  const int q = lane & 15, g = lane >> 4;
  const int wm = w >> 1, wn = w & 1;
  const int bx = blockIdx.x, by = blockIdx.y;

  f32x4 acc[4][2] = {};

  // staging geometry (shared by all tiles)
  const int Lb4 = lane * 16;
  auto stage = [&](int kt, int buf) {
    const int k0 = kt << 6;
#pragma unroll
    for (int i = 0; i < 4; ++i) {
      int Lb = w * 4096 + i * 1024 + Lb4;
      int row = Lb >> 7, cb = Lb & 127;
      const uint16_t* srcA = A + (size_t)(bx * 128 + row) * K + k0 + ((cb ^ ((row & 7) << 4)) >> 1);
      __builtin_amdgcn_global_load_lds(GAS(srcA), LAS(ldsA[buf] + w * 4096 + i * 1024), 16, 0, 0);
    }
#pragma unroll
    for (int i = 0; i < 2; ++i) {
      int Lb = w * 2048 + i * 1024 + Lb4;
      int row = Lb >> 7, cb = Lb & 127;
      const uint16_t* srcB = W + (size_t)(by * 64 + row) * K + k0 + ((cb ^ ((row & 7) << 4)) >> 1);
      __builtin_amdgcn_global_load_lds(GAS(srcB), LAS(ldsB[buf] + w * 2048 + i * 1024), 16, 0, 0);
    }
  };

  stage(0, 0);  // prologue

  const int nkt = K >> 6;
  for (int kt = 0; kt < nkt; ++kt) {
    const int cur = kt & 1;
    asm volatile("s_waitcnt vmcnt(0)" ::: "memory");  // glls(cur) done (issued last iter)
    __builtin_amdgcn_sched_barrier(0);
    __builtin_amdgcn_s_barrier();                     // + all waves done reading buf nxt
    __builtin_amdgcn_sched_barrier(0);
    if (kt + 1 < nkt) stage(kt + 1, cur ^ 1);         // flies under this tile's compute

    bf16x8 af[4][2], bfg[2][2];
#pragma unroll
    for (int mi = 0; mi < 4; ++mi)
#pragma unroll
      for (int s = 0; s < 2; ++s) {
        int row = wm * 64 + mi * 16 + q;
        int cb = (16 * g + 64 * s) ^ ((row & 7) << 4);
        af[mi][s] = *(const bf16x8*)(ldsA[cur] + row * 128 + cb);
      }
#pragma unroll
    for (int ni = 0; ni < 2; ++ni)
#pragma unroll
      for (int s = 0; s < 2; ++s) {
        int row = wn * 32 + ni * 16 + q;
        int cb = (16 * g + 64 * s) ^ ((row & 7) << 4);
        bfg[ni][s] = *(const bf16x8*)(ldsB[cur] + row * 128 + cb);
      }
#pragma unroll
    for (int mi = 0; mi < 4; ++mi)
#pragma unroll
      for (int ni = 0; ni < 2; ++ni) {
        acc[mi][ni] = __builtin_amdgcn_mfma_f32_16x16x32_bf16(af[mi][0], bfg[ni][0], acc[mi][ni], 0, 0, 0);
        acc[mi][ni] = __builtin_amdgcn_mfma_f32_16x16x32_bf16(af[mi][1], bfg[ni][1], acc[mi][ni], 0, 0, 0);
      }
  }

  float bias[2];
#pragma unroll
  for (int ni = 0; ni < 2; ++ni) bias[ni] = bp[by * 64 + wn * 32 + ni * 16 + q];
#pragma unroll
  for (int mi = 0; mi < 4; ++mi)
#pragma unroll
    for (int ni = 0; ni < 2; ++ni)
#pragma unroll
      for (int r = 0; r < 4; ++r) {
        int m = bx * 128 + wm * 64 + mi * 16 + 4 * g + r;
        int n = by * 64 + wn * 32 + ni * 16 + q;
        O[(size_t)m * N + n] = acc[mi][ni][r] + bias[ni];
      }
}

// ---------------- sliding-window attention (round-9 structure + setprio) ----------------
__global__ __launch_bounds__(512, 4) void attn_swa(
    const uint16_t* __restrict__ Qg, const uint16_t* __restrict__ Kg,
    const uint16_t* __restrict__ Vg, uint16_t* __restrict__ Og) {
  __shared__ __align__(16) uint8_t ldsK[2][64 * 128];
  __shared__ __align__(16) uint8_t ldsVt[2][64 * 128];
  __shared__ __align__(16) uint8_t ldsP[8][2048];

  const int tid = threadIdx.x, w = tid >> 6, lane = tid & 63;
  const int q = lane & 15, g = lane >> 4;
  const int qb = blockIdx.x, bh = blockIdx.y;
  const size_t hbase = (size_t)bh * Ss * DH;
  const uint16_t* Qp = Qg + hbase;
  const uint16_t* Kp = Kg + hbase;
  const uint16_t* Vp = Vg + hbase;
  const int q0 = qb * 128;
  const int qw = q0 + w * 16;

  bf16x8 aq[2];
#pragma unroll
  for (int s = 0; s < 2; ++s) {
    bf16x8 t = *(const bf16x8*)(Qp + (size_t)(qw + q) * DH + s * 32 + g * 8);
#pragma unroll
    for (int j = 0; j < 8; ++j) {
      float f = bf2f((uint16_t)t[j]) * 0.125f;
      t[j] = (short)f2bf(f);
    }
    aq[s] = t;
  }

  f32x4 accO[4] = {};
  float lrun[4] = {0.f, 0.f, 0.f, 0.f};

  const int t0 = (q0 >= 256) ? (q0 - 256) : 0;
  const int t1 = (q0 + 384 <= Ss) ? (q0 + 384) : Ss;
  const int nt = (t1 - t0) >> 6;

  {
    int Lb = w * 1024 + lane * 16;
    int row = Lb >> 7, cb = Lb & 127;
    const uint16_t* srcK = Kp + (size_t)(t0 + row) * DH + ((cb ^ ((row & 7) << 4)) >> 1);
    __builtin_amdgcn_global_load_lds(GAS(srcK), LAS(ldsK[0] + w * 1024), 16, 0, 0);
  }
  bf16x8 v0 = *(const bf16x8*)(Vp + (size_t)(t0 + lane) * DH + w * 8);

  for (int t = 0; t < nt; ++t) {
    const int kb0 = t0 + (t << 6);
    const int cur = t & 1, nxt = cur ^ 1;

    asm volatile("s_waitcnt vmcnt(0)" ::: "memory");
    uint8_t* Vt = ldsVt[cur];
#pragma unroll
    for (int j = 0; j < 8; ++j) {
      int c = w * 8 + j;
      *(uint16_t*)(Vt + c * 128 + ((2 * lane) ^ (j << 4))) = (uint16_t)v0[j];
    }
    asm volatile("s_waitcnt lgkmcnt(0)" ::: "memory");
    __builtin_amdgcn_sched_barrier(0);
    __builtin_amdgcn_s_barrier();
    __builtin_amdgcn_sched_barrier(0);

    if (t + 1 < nt) {
      int Lb = w * 1024 + lane * 16;
      int row = Lb >> 7, cb = Lb & 127;
      const uint16_t* srcK = Kp + (size_t)(kb0 + 64 + row) * DH + ((cb ^ ((row & 7) << 4)) >> 1);
      __builtin_amdgcn_global_load_lds(GAS(srcK), LAS(ldsK[nxt] + w * 1024), 16, 0, 0);
      v0 = *(const bf16x8*)(Vp + (size_t)(kb0 + 64 + lane) * DH + w * 8);
    }

    const int dtile = kb0 - qw;
    if (dtile >= -319 && dtile <= 271) {
      const uint8_t* Kl = ldsK[cur];
      f32x4 sacc[4] = {};
      __builtin_amdgcn_s_setprio(1);
#pragma unroll
      for (int kb = 0; kb < 4; ++kb) {
        int row = kb * 16 + q;
#pragma unroll
        for (int s = 0; s < 2; ++s) {
          int cb = (16 * g + 64 * s) ^ ((row & 7) << 4);
          bf16x8 bk = *(const bf16x8*)(Kl + row * 128 + cb);
          sacc[kb] = __builtin_amdgcn_mfma_f32_16x16x32_bf16(aq[s], bk, sacc[kb], 0, 0, 0);
        }
      }
      __builtin_amdgcn_s_setprio(0);
      if (dtile < -192 || dtile > 192) {
#pragma unroll
        for (int kb = 0; kb < 4; ++kb) {
          int key = kb0 + kb * 16 + q;
#pragma unroll
          for (int r = 0; r < 4; ++r) {
            int qi = qw + 4 * g + r;
            int dd = qi - key;
            bool ok = (dd <= 256) && (dd >= -256);
            sacc[kb][r] = ok ? sacc[kb][r] : -1e30f;
          }
        }
      }
      uint8_t* Pl = ldsP[w];
#pragma unroll
      for (int r = 0; r < 4; ++r) {
        float p0 = fexp2(sacc[0][r] * LOG2E);
        float p1 = fexp2(sacc[1][r] * LOG2E);
        float p2 = fexp2(sacc[2][r] * LOG2E);
        float p3 = fexp2(sacc[3][r] * LOG2E);
        float rs = rowsum16((p0 + p1) + (p2 + p3));
        lrun[r] += rs;
        int prow = 4 * g + r;
        int sw = (prow & 7) << 4;
        uint8_t* Pr = Pl + prow * 128;
        uint32_t pk01 = cvtpk(p0, p1), pk23 = cvtpk(p2, p3);
        *(uint16_t*)(Pr + ((2 * q) ^ sw))      = (uint16_t)pk01;
        *(uint16_t*)(Pr + ((2 * q + 32) ^ sw)) = (uint16_t)(pk01 >> 16);
        *(uint16_t*)(Pr + ((2 * q + 64) ^ sw)) = (uint16_t)pk23;
        *(uint16_t*)(Pr + ((2 * q + 96) ^ sw)) = (uint16_t)(pk23 >> 16);
      }
      bf16x8 ap[2];
#pragma unroll
      for (int s = 0; s < 2; ++s) {
        int cb = (16 * g + 64 * s) ^ ((q & 7) << 4);
        ap[s] = *(const bf16x8*)(Pl + q * 128 + cb);
      }
      __builtin_amdgcn_s_setprio(1);
#pragma unroll
      for (int db = 0; db < 4; ++db) {
        int vr = db * 16 + q;
#pragma unroll
        for (int s = 0; s < 2; ++s) {
          int cb = (64 * s + 16 * g) ^ ((vr & 7) << 4);
          bf16x8 bvf = *(const bf16x8*)(ldsVt[cur] + vr * 128 + cb);
          accO[db] = __builtin_amdgcn_mfma_f32_16x16x32_bf16(ap[s], bvf, accO[db], 0, 0, 0);
        }
      }
      __builtin_amdgcn_s_setprio(0);
    }
  }

  const int b2 = bh >> 4, h = bh & 15;
#pragma unroll
  for (int r = 0; r < 4; ++r) {
    float inv = 1.0f / lrun[r];
    int qi = qw + 4 * g + r;
    size_t rowbase = ((size_t)(b2 * Ss + qi)) * Dd + h * DH;
#pragma unroll
    for (int db = 0; db < 4; ++db) {
      Og[rowbase + db * 16 + q] = f2bf(accO[db][r] * inv);
    }
  }
}

// ---------------- host launch ----------------
extern "C" void kernel_launch(void* const* d_in, const int* in_sizes, int n_in,
                              void* d_out, int out_size, void* d_ws, size_t ws_size,
                              hipStream_t stream) {
  const float* x  = (const float*)d_in[0];
  const float* wq = (const float*)d_in[1];
  const float* bq = (const float*)d_in[2];
  const float* wk = (const float*)d_in[3];
  const float* bk = (const float*)d_in[4];
  const float* wv = (const float*)d_in[5];
  const float* bv = (const float*)d_in[6];
  const float* wo = (const float*)d_in[7];
  const float* bo = (const float*)d_in[8];
  float* out = (float*)d_out;

  uint8_t* ws = (uint8_t*)d_ws;
  uint16_t* xb  = (uint16_t*)(ws + (size_t)(0u  << 20));  // 8 MB
  uint16_t* wqb = (uint16_t*)(ws + (size_t)(8u  << 20));  // 2 MB each
  uint16_t* wkb = (uint16_t*)(ws + (size_t)(10u << 20));
  uint16_t* wvb = (uint16_t*)(ws + (size_t)(12u << 20));
  uint16_t* wob = (uint16_t*)(ws + (size_t)(14u << 20));
  uint16_t* Qb  = (uint16_t*)(ws + (size_t)(16u << 20));  // 8 MB each
  uint16_t* Kb  = (uint16_t*)(ws + (size_t)(24u << 20));
  uint16_t* Vb  = (uint16_t*)(ws + (size_t)(32u << 20));
  uint16_t* AOb = (uint16_t*)(ws + (size_t)(40u << 20));  // attention output bf16 [4096,1024]

  // f32 -> bf16: x + 4 weights in one launch
  cvt_all<<<8192, 256, 0, stream>>>(x, wq, wk, wv, wo, xb, wqb, wkb, wvb, wob);

  // fused QKV projection (z picks q/k/v); BN=128 -> 768 WGs
  gemm_qkv<<<dim3(32, 8, 3), 256, 0, stream>>>(
      xb, wqb, wkb, wvb, bq, bk, bv, Qb, Kb, Vb);

  // sliding-window attention: QBLK=128, 8 waves x 16 q-rows
  attn_swa<<<dim3(16, 32), 512, 0, stream>>>(Qb, Kb, Vb, AOb);

  // output projection -> f32 d_out; BN=64 -> 512 WGs, dbuf prefetch
  gemm_out<<<dim3(32, 16), 256, 0, stream>>>(
      AOb, wob, bo, out, 4096, 1024, 1024);
}

// Round 12
// 78.200 us; speedup vs baseline: 1.0431x; 1.0095x over previous
//
#include <hip/hip_runtime.h>
#include <stdint.h>

// Problem constants: B=2, S=2048, D=1024, H=16, dh=64, WINDOW=256
static constexpr int Ss = 2048;
static constexpr int Dd = 1024;
static constexpr int Hh = 16;
static constexpr int DH = 64;

typedef short bf16x8 __attribute__((ext_vector_type(8)));
typedef float f32x4 __attribute__((ext_vector_type(4)));

#define LOG2E 1.4426950408889634f

__device__ __forceinline__ uint16_t f2bf(float f) {
  uint32_t u = __builtin_bit_cast(uint32_t, f);
  u += 0x7fffu + ((u >> 16) & 1u);   // RNE (finite data only)
  return (uint16_t)(u >> 16);
}
__device__ __forceinline__ float bf2f(uint16_t h) {
  uint32_t u = ((uint32_t)h) << 16;
  return __builtin_bit_cast(float, u);
}
__device__ __forceinline__ uint32_t cvtpk(float a, float b) {
  uint32_t r;
  asm("v_cvt_pk_bf16_f32 %0, %1, %2" : "=v"(r) : "v"(a), "v"(b));
  return r;
}

// DPP lane-rotate within 16-lane rows (pure VALU, no LDS pipe).
template <int CTRL>
__device__ __forceinline__ float dppf(float x) {
  return __builtin_bit_cast(float,
      __builtin_amdgcn_update_dpp(0, __builtin_bit_cast(int, x), CTRL, 0xF, 0xF, true));
}
__device__ __forceinline__ float rowsum16(float v) {
  v += dppf<0x128>(v);
  v += dppf<0x124>(v);
  v += dppf<0x122>(v);
  v += dppf<0x121>(v);
  return v;
}
__device__ __forceinline__ float fexp2(float x) { return __builtin_amdgcn_exp2f(x); }

#define GAS(p) ((const __attribute__((address_space(1))) uint32_t*)(p))
#define LAS(p) ((__attribute__((address_space(3))) uint32_t*)(p))

// ---------------- f32 -> bf16: x (4096 blocks) + 4 weights (1024 blocks each) ----------------
__global__ void cvt_all(const float* __restrict__ x,
                        const float* __restrict__ w0, const float* __restrict__ w1,
                        const float* __restrict__ w2, const float* __restrict__ w3,
                        uint16_t* __restrict__ xb,
                        uint16_t* __restrict__ o0, uint16_t* __restrict__ o1,
                        uint16_t* __restrict__ o2, uint16_t* __restrict__ o3) {
  int bid = blockIdx.x;
  const float* in;
  uint16_t* out;
  int i;
  if (bid < 4096) {                       // x: 1048576 float4 exactly
    in = x; out = xb; i = bid * 256 + threadIdx.x;
  } else {                                // weights: 262144 float4 each exactly
    int b2 = bid - 4096;
    int t = b2 >> 10;
    in = (t == 0) ? w0 : (t == 1) ? w1 : (t == 2) ? w2 : w3;
    out = (t == 0) ? o0 : (t == 1) ? o1 : (t == 2) ? o2 : o3;
    i = (b2 & 1023) * 256 + threadIdx.x;
  }
  float4 v = reinterpret_cast<const float4*>(in)[i];
  ushort4 o;
  o.x = f2bf(v.x); o.y = f2bf(v.y); o.z = f2bf(v.z); o.w = f2bf(v.w);
  reinterpret_cast<ushort4*>(out)[i] = o;
}

// ---------------- fused-z QKV GEMM: one WG computes Q,K,V for its (bx,by) ----------------
// BM=128, BN=64 per z (3 z's share the A-tile), BK=64, 256 threads (4 waves 2x2).
// A+B double-buffered (80 KB LDS = exactly 2 blocks/CU); single barrier per K-step:
// stage(t+1) issued after the barrier flies under this step's 48 MFMAs; vmcnt(0)
// at the top of t+1 drains loads issued a full compute phase earlier.
__global__ __launch_bounds__(256, 2) void gemm_qkv(
    const uint16_t* __restrict__ A,
    const uint16_t* __restrict__ W0, const uint16_t* __restrict__ W1, const uint16_t* __restrict__ W2,
    const float* __restrict__ b0, const float* __restrict__ b1, const float* __restrict__ b2,
    uint16_t* __restrict__ O0, uint16_t* __restrict__ O1, uint16_t* __restrict__ O2) {
  constexpr int K = 1024;
  __shared__ __align__(16) uint8_t ldsA[2][128 * 128];     // [128 m][64 k] bf16, swizzled
  __shared__ __align__(16) uint8_t ldsB[2][3][64 * 128];   // per z: [64 n][64 k] bf16, swizzled

  const int tid = threadIdx.x, w = tid >> 6, lane = tid & 63;
  const int q = lane & 15, g = lane >> 4;
  const int wm = w >> 1, wn = w & 1;
  const int bx = blockIdx.x, by = blockIdx.y;
  const uint16_t* Wz[3] = {W0, W1, W2};

  f32x4 acc[3][4][2] = {};

  const int Lb16 = lane * 16;
  auto stage = [&](int kt, int buf) {
    const int k0 = kt << 6;
#pragma unroll
    for (int i = 0; i < 4; ++i) {
      int Lb = w * 4096 + i * 1024 + Lb16;
      int row = Lb >> 7, cb = Lb & 127;
      const uint16_t* srcA = A + (size_t)(bx * 128 + row) * K + k0 + ((cb ^ ((row & 7) << 4)) >> 1);
      __builtin_amdgcn_global_load_lds(GAS(srcA), LAS(ldsA[buf] + w * 4096 + i * 1024), 16, 0, 0);
    }
#pragma unroll
    for (int z = 0; z < 3; ++z)
#pragma unroll
      for (int i = 0; i < 2; ++i) {
        int Lb = w * 2048 + i * 1024 + Lb16;
        int row = Lb >> 7, cb = Lb & 127;
        const uint16_t* srcB = Wz[z] + (size_t)(by * 64 + row) * K + k0 + ((cb ^ ((row & 7) << 4)) >> 1);
        __builtin_amdgcn_global_load_lds(GAS(srcB), LAS(ldsB[buf][z] + w * 2048 + i * 1024), 16, 0, 0);
      }
  };

  stage(0, 0);  // prologue

  const int nkt = K >> 6;
  for (int kt = 0; kt < nkt; ++kt) {
    const int cur = kt & 1;
    asm volatile("s_waitcnt vmcnt(0)" ::: "memory");  // glls(cur) done (issued last iter)
    __builtin_amdgcn_sched_barrier(0);
    __builtin_amdgcn_s_barrier();                     // + all waves done reading buf nxt
    __builtin_amdgcn_sched_barrier(0);
    if (kt + 1 < nkt) stage(kt + 1, cur ^ 1);         // flies under this step's compute

    bf16x8 af[4][2];
#pragma unroll
    for (int mi = 0; mi < 4; ++mi)
#pragma unroll
      for (int s = 0; s < 2; ++s) {
        int row = wm * 64 + mi * 16 + q;
        int cb = (16 * g + 64 * s) ^ ((row & 7) << 4);
        af[mi][s] = *(const bf16x8*)(ldsA[cur] + row * 128 + cb);
      }
#pragma unroll
    for (int z = 0; z < 3; ++z) {
      bf16x8 bfg[2][2];
#pragma unroll
      for (int ni = 0; ni < 2; ++ni)
#pragma unroll
        for (int s = 0; s < 2; ++s) {
          int row = wn * 32 + ni * 16 + q;
          int cb = (16 * g + 64 * s) ^ ((row & 7) << 4);
          bfg[ni][s] = *(const bf16x8*)(ldsB[cur][z] + row * 128 + cb);
        }
#pragma unroll
      for (int mi = 0; mi < 4; ++mi)
#pragma unroll
        for (int ni = 0; ni < 2; ++ni) {
          acc[z][mi][ni] = __builtin_amdgcn_mfma_f32_16x16x32_bf16(af[mi][0], bfg[ni][0], acc[z][mi][ni], 0, 0, 0);
          acc[z][mi][ni] = __builtin_amdgcn_mfma_f32_16x16x32_bf16(af[mi][1], bfg[ni][1], acc[z][mi][ni], 0, 0, 0);
        }
    }
  }

  // epilogue: bias + store to [B,H,S,dh].  C/D: col=lane&15, row=(lane>>4)*4+reg
  const float* bz[3] = {b0, b1, b2};
  uint16_t* Oz[3] = {O0, O1, O2};
#pragma unroll
  for (int z = 0; z < 3; ++z) {
    float bias[2];
#pragma unroll
    for (int ni = 0; ni < 2; ++ni) bias[ni] = bz[z][by * 64 + wn * 32 + ni * 16 + q];
#pragma unroll
    for (int mi = 0; mi < 4; ++mi)
#pragma unroll
      for (int ni = 0; ni < 2; ++ni)
#pragma unroll
        for (int r = 0; r < 4; ++r) {
          int m = bx * 128 + wm * 64 + mi * 16 + 4 * g + r;
          int n = by * 64 + wn * 32 + ni * 16 + q;
          float v = acc[z][mi][ni][r] + bias[ni];
          int b = m >> 11, s = m & 2047, h = n >> 6, d = n & 63;
          Oz[z][(((size_t)(b * Hh + h) * Ss + s) << 6) + d] = f2bf(v);
        }
  }
}

// ---------------- out-projection GEMM: single-barrier double-buffered prefetch ----------------
__global__ __launch_bounds__(256, 2) void gemm_out(
    const uint16_t* __restrict__ A, const uint16_t* __restrict__ W,
    const float* __restrict__ bp, float* __restrict__ O, int M, int N, int K) {
  __shared__ __align__(16) uint8_t ldsA[2][128 * 128];
  __shared__ __align__(16) uint8_t ldsB[2][64 * 128];

  const int tid = threadIdx.x, w = tid >> 6, lane = tid & 63;
  const int q = lane & 15, g = lane >> 4;
  const int wm = w >> 1, wn = w & 1;
  const int bx = blockIdx.x, by = blockIdx.y;

  f32x4 acc[4][2] = {};

  const int Lb4 = lane * 16;
  auto stage = [&](int kt, int buf) {
    const int k0 = kt << 6;
#pragma unroll
    for (int i = 0; i < 4; ++i) {
      int Lb = w * 4096 + i * 1024 + Lb4;
      int row = Lb >> 7, cb = Lb & 127;
      const uint16_t* srcA = A + (size_t)(bx * 128 + row) * K + k0 + ((cb ^ ((row & 7) << 4)) >> 1);
      __builtin_amdgcn_global_load_lds(GAS(srcA), LAS(ldsA[buf] + w * 4096 + i * 1024), 16, 0, 0);
    }
#pragma unroll
    for (int i = 0; i < 2; ++i) {
      int Lb = w * 2048 + i * 1024 + Lb4;
      int row = Lb >> 7, cb = Lb & 127;
      const uint16_t* srcB = W + (size_t)(by * 64 + row) * K + k0 + ((cb ^ ((row & 7) << 4)) >> 1);
      __builtin_amdgcn_global_load_lds(GAS(srcB), LAS(ldsB[buf] + w * 2048 + i * 1024), 16, 0, 0);
    }
  };

  stage(0, 0);

  const int nkt = K >> 6;
  for (int kt = 0; kt < nkt; ++kt) {
    const int cur = kt & 1;
    asm volatile("s_waitcnt vmcnt(0)" ::: "memory");
    __builtin_amdgcn_sched_barrier(0);
    __builtin_amdgcn_s_barrier();
    __builtin_amdgcn_sched_barrier(0);
    if (kt + 1 < nkt) stage(kt + 1, cur ^ 1);

    bf16x8 af[4][2], bfg[2][2];
#pragma unroll
    for (int mi = 0; mi < 4; ++mi)
#pragma unroll
      for (int s = 0; s < 2; ++s) {
        int row = wm * 64 + mi * 16 + q;
        int cb = (16 * g + 64 * s) ^ ((row & 7) << 4);
        af[mi][s] = *(const bf16x8*)(ldsA[cur] + row * 128 + cb);
      }
#pragma unroll
    for (int ni = 0; ni < 2; ++ni)
#pragma unroll
      for (int s = 0; s < 2; ++s) {
        int row = wn * 32 + ni * 16 + q;
        int cb = (16 * g + 64 * s) ^ ((row & 7) << 4);
        bfg[ni][s] = *(const bf16x8*)(ldsB[cur] + row * 128 + cb);
      }
#pragma unroll
    for (int mi = 0; mi < 4; ++mi)
#pragma unroll
      for (int ni = 0; ni < 2; ++ni) {
        acc[mi][ni] = __builtin_amdgcn_mfma_f32_16x16x32_bf16(af[mi][0], bfg[ni][0], acc[mi][ni], 0, 0, 0);
        acc[mi][ni] = __builtin_amdgcn_mfma_f32_16x16x32_bf16(af[mi][1], bfg[ni][1], acc[mi][ni], 0, 0, 0);
      }
  }

  float bias[2];
#pragma unroll
  for (int ni = 0; ni < 2; ++ni) bias[ni] = bp[by * 64 + wn * 32 + ni * 16 + q];
#pragma unroll
  for (int mi = 0; mi < 4; ++mi)
#pragma unroll
    for (int ni = 0; ni < 2; ++ni)
#pragma unroll
      for (int r = 0; r < 4; ++r) {
        int m = bx * 128 + wm * 64 + mi * 16 + 4 * g + r;
        int n = by * 64 + wn * 32 + ni * 16 + q;
        O[(size_t)m * N + n] = acc[mi][ni][r] + bias[ni];
      }
}

// ---------------- sliding-window attention (round-11 structure) ----------------
__global__ __launch_bounds__(512, 4) void attn_swa(
    const uint16_t* __restrict__ Qg, const uint16_t* __restrict__ Kg,
    const uint16_t* __restrict__ Vg, uint16_t* __restrict__ Og) {
  __shared__ __align__(16) uint8_t ldsK[2][64 * 128];
  __shared__ __align__(16) uint8_t ldsVt[2][64 * 128];
  __shared__ __align__(16) uint8_t ldsP[8][2048];

  const int tid = threadIdx.x, w = tid >> 6, lane = tid & 63;
  const int q = lane & 15, g = lane >> 4;
  const int qb = blockIdx.x, bh = blockIdx.y;
  const size_t hbase = (size_t)bh * Ss * DH;
  const uint16_t* Qp = Qg + hbase;
  const uint16_t* Kp = Kg + hbase;
  const uint16_t* Vp = Vg + hbase;
  const int q0 = qb * 128;
  const int qw = q0 + w * 16;

  bf16x8 aq[2];
#pragma unroll
  for (int s = 0; s < 2; ++s) {
    bf16x8 t = *(const bf16x8*)(Qp + (size_t)(qw + q) * DH + s * 32 + g * 8);
#pragma unroll
    for (int j = 0; j < 8; ++j) {
      float f = bf2f((uint16_t)t[j]) * 0.125f;
      t[j] = (short)f2bf(f);
    }
    aq[s] = t;
  }

  f32x4 accO[4] = {};
  float lrun[4] = {0.f, 0.f, 0.f, 0.f};

  const int t0 = (q0 >= 256) ? (q0 - 256) : 0;
  const int t1 = (q0 + 384 <= Ss) ? (q0 + 384) : Ss;
  const int nt = (t1 - t0) >> 6;

  {
    int Lb = w * 1024 + lane * 16;
    int row = Lb >> 7, cb = Lb & 127;
    const uint16_t* srcK = Kp + (size_t)(t0 + row) * DH + ((cb ^ ((row & 7) << 4)) >> 1);
    __builtin_amdgcn_global_load_lds(GAS(srcK), LAS(ldsK[0] + w * 1024), 16, 0, 0);
  }
  bf16x8 v0 = *(const bf16x8*)(Vp + (size_t)(t0 + lane) * DH + w * 8);

  for (int t = 0; t < nt; ++t) {
    const int kb0 = t0 + (t << 6);
    const int cur = t & 1, nxt = cur ^ 1;

    asm volatile("s_waitcnt vmcnt(0)" ::: "memory");
    uint8_t* Vt = ldsVt[cur];
#pragma unroll
    for (int j = 0; j < 8; ++j) {
      int c = w * 8 + j;
      *(uint16_t*)(Vt + c * 128 + ((2 * lane) ^ (j << 4))) = (uint16_t)v0[j];
    }
    asm volatile("s_waitcnt lgkmcnt(0)" ::: "memory");
    __builtin_amdgcn_sched_barrier(0);
    __builtin_amdgcn_s_barrier();
    __builtin_amdgcn_sched_barrier(0);

    if (t + 1 < nt) {
      int Lb = w * 1024 + lane * 16;
      int row = Lb >> 7, cb = Lb & 127;
      const uint16_t* srcK = Kp + (size_t)(kb0 + 64 + row) * DH + ((cb ^ ((row & 7) << 4)) >> 1);
      __builtin_amdgcn_global_load_lds(GAS(srcK), LAS(ldsK[nxt] + w * 1024), 16, 0, 0);
      v0 = *(const bf16x8*)(Vp + (size_t)(kb0 + 64 + lane) * DH + w * 8);
    }

    const int dtile = kb0 - qw;
    if (dtile >= -319 && dtile <= 271) {
      const uint8_t* Kl = ldsK[cur];
      f32x4 sacc[4] = {};
      __builtin_amdgcn_s_setprio(1);
#pragma unroll
      for (int kb = 0; kb < 4; ++kb) {
        int row = kb * 16 + q;
#pragma unroll
        for (int s = 0; s < 2; ++s) {
          int cb = (16 * g + 64 * s) ^ ((row & 7) << 4);
          bf16x8 bk = *(const bf16x8*)(Kl + row * 128 + cb);
          sacc[kb] = __builtin_amdgcn_mfma_f32_16x16x32_bf16(aq[s], bk, sacc[kb], 0, 0, 0);
        }
      }
      __builtin_amdgcn_s_setprio(0);
      if (dtile < -192 || dtile > 192) {
#pragma unroll
        for (int kb = 0; kb < 4; ++kb) {
          int key = kb0 + kb * 16 + q;
#pragma unroll
          for (int r = 0; r < 4; ++r) {
            int qi = qw + 4 * g + r;
            int dd = qi - key;
            bool ok = (dd <= 256) && (dd >= -256);
            sacc[kb][r] = ok ? sacc[kb][r] : -1e30f;
          }
        }
      }
      uint8_t* Pl = ldsP[w];
#pragma unroll
      for (int r = 0; r < 4; ++r) {
        float p0 = fexp2(sacc[0][r] * LOG2E);
        float p1 = fexp2(sacc[1][r] * LOG2E);
        float p2 = fexp2(sacc[2][r] * LOG2E);
        float p3 = fexp2(sacc[3][r] * LOG2E);
        float rs = rowsum16((p0 + p1) + (p2 + p3));
        lrun[r] += rs;
        int prow = 4 * g + r;
        int sw = (prow & 7) << 4;
        uint8_t* Pr = Pl + prow * 128;
        uint32_t pk01 = cvtpk(p0, p1), pk23 = cvtpk(p2, p3);
        *(uint16_t*)(Pr + ((2 * q) ^ sw))      = (uint16_t)pk01;
        *(uint16_t*)(Pr + ((2 * q + 32) ^ sw)) = (uint16_t)(pk01 >> 16);
        *(uint16_t*)(Pr + ((2 * q + 64) ^ sw)) = (uint16_t)pk23;
        *(uint16_t*)(Pr + ((2 * q + 96) ^ sw)) = (uint16_t)(pk23 >> 16);
      }
      bf16x8 ap[2];
#pragma unroll
      for (int s = 0; s < 2; ++s) {
        int cb = (16 * g + 64 * s) ^ ((q & 7) << 4);
        ap[s] = *(const bf16x8*)(Pl + q * 128 + cb);
      }
      __builtin_amdgcn_s_setprio(1);
#pragma unroll
      for (int db = 0; db < 4; ++db) {
        int vr = db * 16 + q;
#pragma unroll
        for (int s = 0; s < 2; ++s) {
          int cb = (64 * s + 16 * g) ^ ((vr & 7) << 4);
          bf16x8 bvf = *(const bf16x8*)(ldsVt[cur] + vr * 128 + cb);
          accO[db] = __builtin_amdgcn_mfma_f32_16x16x32_bf16(ap[s], bvf, accO[db], 0, 0, 0);
        }
      }
      __builtin_amdgcn_s_setprio(0);
    }
  }

  const int b2 = bh >> 4, h = bh & 15;
#pragma unroll
  for (int r = 0; r < 4; ++r) {
    float inv = 1.0f / lrun[r];
    int qi = qw + 4 * g + r;
    size_t rowbase = ((size_t)(b2 * Ss + qi)) * Dd + h * DH;
#pragma unroll
    for (int db = 0; db < 4; ++db) {
      Og[rowbase + db * 16 + q] = f2bf(accO[db][r] * inv);
    }
  }
}

// ---------------- host launch ----------------
extern "C" void kernel_launch(void* const* d_in, const int* in_sizes, int n_in,
                              void* d_out, int out_size, void* d_ws, size_t ws_size,
                              hipStream_t stream) {
  const float* x  = (const float*)d_in[0];
  const float* wq = (const float*)d_in[1];
  const float* bq = (const float*)d_in[2];
  const float* wk = (const float*)d_in[3];
  const float* bk = (const float*)d_in[4];
  const float* wv = (const float*)d_in[5];
  const float* bv = (const float*)d_in[6];
  const float* wo = (const float*)d_in[7];
  const float* bo = (const float*)d_in[8];
  float* out = (float*)d_out;

  uint8_t* ws = (uint8_t*)d_ws;
  uint16_t* xb  = (uint16_t*)(ws + (size_t)(0u  << 20));  // 8 MB
  uint16_t* wqb = (uint16_t*)(ws + (size_t)(8u  << 20));  // 2 MB each
  uint16_t* wkb = (uint16_t*)(ws + (size_t)(10u << 20));
  uint16_t* wvb = (uint16_t*)(ws + (size_t)(12u << 20));
  uint16_t* wob = (uint16_t*)(ws + (size_t)(14u << 20));
  uint16_t* Qb  = (uint16_t*)(ws + (size_t)(16u << 20));  // 8 MB each
  uint16_t* Kb  = (uint16_t*)(ws + (size_t)(24u << 20));
  uint16_t* Vb  = (uint16_t*)(ws + (size_t)(32u << 20));
  uint16_t* AOb = (uint16_t*)(ws + (size_t)(40u << 20));  // attention output bf16 [4096,1024]

  // f32 -> bf16: x + 4 weights in one launch
  cvt_all<<<8192, 256, 0, stream>>>(x, wq, wk, wv, wo, xb, wqb, wkb, wvb, wob);

  // fused-z QKV projection: 512 WGs (2/CU), dbuf single-barrier
  gemm_qkv<<<dim3(32, 16), 256, 0, stream>>>(
      xb, wqb, wkb, wvb, bq, bk, bv, Qb, Kb, Vb);

  // sliding-window attention: QBLK=128, 8 waves x 16 q-rows
  attn_swa<<<dim3(16, 32), 512, 0, stream>>>(Qb, Kb, Vb, AOb);

  // output projection -> f32 d_out; BN=64 -> 512 WGs, dbuf prefetch
  gemm_out<<<dim3(32, 16), 256, 0, stream>>>(
      AOb, wob, bo, out, 4096, 1024, 1024);
}